// Round 2
// baseline (44.920 us; speedup 1.0000x reference)
//
#include <hip/hip_runtime.h>

typedef __attribute__((ext_vector_type(4))) float float4v;

// Input:  (N*C=16, D=128, H=128, W=128) float32
// Output: 8 bands, each (16, 64, 64, 64) float32, concatenated flat.
// Each thread: one (nc, e, p) segment of 4 output q values (8 input w).
__global__ __launch_bounds__(256) void dwt3d_haar_kernel(
        const float* __restrict__ x, float* __restrict__ out) {
    const int tid = blockIdx.x * 256 + threadIdx.x;

    const int qb = tid & 15;          // q-block: q = 4*qb .. 4*qb+3
    const int p  = (tid >> 4) & 63;   // H/2 index
    const int e  = (tid >> 10) & 63;  // D/2 index
    const int nc = tid >> 16;         // 0..15

    // input base: (nc, d=2e, h=2p, w=8*qb)
    const long inBase = ((long)((nc * 128 + 2 * e) * 128 + 2 * p)) * 128 + 8 * qb;
    const float* r0 = x + inBase;            // d0, h0
    const float* r1 = r0 + 128;              // d0, h1
    const float* r2 = r0 + 128 * 128;        // d1, h0
    const float* r3 = r2 + 128;              // d1, h1

    // Load 4 rows x 8 floats (two float4 loads per row)
    float4v va[4], vb[4];
    va[0] = *(const float4v*)(r0); vb[0] = *(const float4v*)(r0 + 4);
    va[1] = *(const float4v*)(r1); vb[1] = *(const float4v*)(r1 + 4);
    va[2] = *(const float4v*)(r2); vb[2] = *(const float4v*)(r2 + 4);
    va[3] = *(const float4v*)(r3); vb[3] = *(const float4v*)(r3 + 4);

    // W-direction butterfly per row: lo = even+odd, hi = even-odd
    float rlo[4][4], rhi[4][4];
#pragma unroll
    for (int r = 0; r < 4; ++r) {
        rlo[r][0] = va[r][0] + va[r][1];
        rhi[r][0] = va[r][0] - va[r][1];
        rlo[r][1] = va[r][2] + va[r][3];
        rhi[r][1] = va[r][2] - va[r][3];
        rlo[r][2] = vb[r][0] + vb[r][1];
        rhi[r][2] = vb[r][0] - vb[r][1];
        rlo[r][3] = vb[r][2] + vb[r][3];
        rhi[r][3] = vb[r][2] - vb[r][3];
    }

    const float S = 0.35355339059327384f;  // (1/sqrt2)^3 = 2^-1.5

    float4v o[8];
#pragma unroll
    for (int j = 0; j < 4; ++j) {
        // H-direction butterfly within each depth slice
        float A0 = rlo[0][j] + rlo[1][j];  // d0: Lh Lw
        float B0 = rhi[0][j] + rhi[1][j];  // d0: Lh Hw
        float C0 = rlo[0][j] - rlo[1][j];  // d0: Hh Lw
        float D0 = rhi[0][j] - rhi[1][j];  // d0: Hh Hw
        float A1 = rlo[2][j] + rlo[3][j];
        float B1 = rhi[2][j] + rhi[3][j];
        float C1 = rlo[2][j] - rlo[3][j];
        float D1 = rhi[2][j] - rhi[3][j];
        // Depth butterfly. Band order: LLL,LLH,LHL,LHH,HLL,HLH,HHL,HHH
        o[0][j] = (A0 + A1) * S;
        o[1][j] = (B0 + B1) * S;
        o[2][j] = (C0 + C1) * S;
        o[3][j] = (D0 + D1) * S;
        o[4][j] = (A0 - A1) * S;
        o[5][j] = (B0 - B1) * S;
        o[6][j] = (C0 - C1) * S;
        o[7][j] = (D0 - D1) * S;
    }

    // Output: band b at offset b * 16*64*64*64, inner ((nc*64+e)*64+p)*64 + q
    const long outInner = ((long)((nc * 64 + e) * 64 + p)) * 64 + 4 * qb;
#pragma unroll
    for (int b = 0; b < 8; ++b) {
        *(float4v*)(out + (long)b * 4194304 + outInner) = o[b];
    }
}

extern "C" void kernel_launch(void* const* d_in, const int* in_sizes, int n_in,
                              void* d_out, int out_size, void* d_ws, size_t ws_size,
                              hipStream_t stream) {
    const float* x = (const float*)d_in[0];
    float* out = (float*)d_out;
    // total threads = 16 (N*C) * 64 (e) * 64 (p) * 16 (q-blocks) = 1048576
    dwt3d_haar_kernel<<<4096, 256, 0, stream>>>(x, out);
}